// Round 2
// baseline (959.858 us; speedup 1.0000x reference)
//
#include <hip/hip_runtime.h>
#include <stdint.h>

typedef unsigned short u16;
typedef __bf16 bf16x8 __attribute__((ext_vector_type(8)));
typedef float f32x4 __attribute__((ext_vector_type(4)));
typedef unsigned short u16x8 __attribute__((ext_vector_type(8)));
typedef unsigned short u16x4 __attribute__((ext_vector_type(4)));

__device__ __forceinline__ float b2f(u16 b) {
    return __uint_as_float(((unsigned)b) << 16);
}
__device__ __forceinline__ u16 f2b(float f) {
    unsigned u = __float_as_uint(f);
    unsigned r = (u + 0x7fffu + ((u >> 16) & 1u)) >> 16;  // RNE
    return (u16)r;
}

#define GLDS16(g, l) __builtin_amdgcn_global_load_lds(                        \
    (const __attribute__((address_space(1))) void*)(g),                       \
    (__attribute__((address_space(3))) void*)(l), 16, 0, 0)

#define BAR()    asm volatile("s_barrier" ::: "memory")
#define WLGKM0() asm volatile("s_waitcnt lgkmcnt(0)" ::: "memory")
#define WVM4()   asm volatile("s_waitcnt vmcnt(4)" ::: "memory")
#define WVM0()   asm volatile("s_waitcnt vmcnt(0)" ::: "memory")

// ---------------------------------------------------------------------------
// 256x256-tile 8-phase GEMM: C = epilogue(A @ Bt^T)
//   A[M,K] bf16 row-major, Bt[N,K] bf16 row-major. 512 thr = 8 waves (2Mx4N),
//   per-wave 128x64 output, BK=64 split into 2 k-halves stored as compact
//   [256][32]-elem LDS blocks (dense 1KB wave reads -> conflict-free).
//   Double-buffered K-tiles; stage kt+1 during kt's phases; vmcnt(4) at odd
//   phase ends (counted, never drained in steady state).  OUT_MODE:
//   0 = bf16 [M,N], 1 = f32 [M,N], 2 = bf16 transposed V^T (b = row>>12,
//   Vt[b][col][row&4095], per-batch stride 1<<22).
// ---------------------------------------------------------------------------
template<int HAS_BIAS, int RELU, int HAS_RES, int OUT_MODE>
__global__ __launch_bounds__(512, 2) void gemm256(
    const u16* __restrict__ A, const u16* __restrict__ Bt,
    const float* __restrict__ bias, const float* __restrict__ res,
    void* __restrict__ Cout, int M, int N, int K,
    long strideA, long strideB, long strideC, long strideR, float scale)
{
    __shared__ u16 smem[65536];   // 128 KiB: A buf0|buf1 (16384 ea), B buf0|buf1

    A   += (long)blockIdx.z * strideA;
    Bt  += (long)blockIdx.z * strideB;
    if (HAS_RES) res += (long)blockIdx.z * strideR;
    u16*   Cb = (u16*)Cout   + (long)blockIdx.z * strideC;
    float* Cf = (float*)Cout + (long)blockIdx.z * strideC;

    // XCD-aware bijective swizzle (nwg % 8 == 0 for all our grids)
    const int nwg = gridDim.x * gridDim.y;
    const int lin = blockIdx.y * gridDim.x + blockIdx.x;
    const int swz = (lin & 7) * (nwg >> 3) + (lin >> 3);
    const int bx = swz % gridDim.x, by = swz / gridDim.x;

    const int t    = threadIdx.x;
    const int lane = t & 63, wid = t >> 6;
    const int wm   = wid >> 2, wn = wid & 3;
    const int lr   = lane & 15, lk = lane >> 4;
    const long m0  = (long)by * 256;
    const long n0  = (long)bx * 256;
    const int  NT  = K >> 6;

    // staging source: chunk c = l*512 + t -> row c>>2, k-chunk (c&3)*8 within
    // a [256][32] half-tile; load l=1 adds 128 rows.
    const u16* gA = A  + (m0 + (t >> 2)) * (long)K + (t & 3) * 8;
    const u16* gB = Bt + (n0 + (t >> 2)) * (long)K + (t & 3) * 8;
    const int ldsW = (t & ~63) * 8;   // wave-uniform dest (HW adds lane*16B)

#define STAGE_A(c, kh, koff) do {                                             \
    GLDS16(gA + (koff) + (kh) * 32,              &smem[(c)*16384 + (kh)*8192 + ldsW]);        \
    GLDS16(gA + 128L*K + (koff) + (kh) * 32,     &smem[(c)*16384 + (kh)*8192 + ldsW + 4096]); } while (0)
#define STAGE_B(c, kh, koff) do {                                             \
    GLDS16(gB + (koff) + (kh) * 32,              &smem[32768 + (c)*16384 + (kh)*8192 + ldsW]);        \
    GLDS16(gB + 128L*K + (koff) + (kh) * 32,     &smem[32768 + (c)*16384 + (kh)*8192 + ldsW + 4096]); } while (0)

    const int raBase = (wm * 128 + lr) * 32 + lk * 8;
    const int rbBase = (wn * 64  + lr) * 32 + lk * 8;

#define LOAD_A(c, kh) do {                                                    \
    _Pragma("unroll")                                                         \
    for (int i = 0; i < 8; ++i)                                               \
        a[i] = *(const bf16x8*)&smem[(c)*16384 + (kh)*8192 + raBase + i*512]; } while (0)
#define LOAD_B(c, kh, nh) do {                                                \
    _Pragma("unroll")                                                         \
    for (int jj = 0; jj < 2; ++jj)                                            \
        b[jj] = *(const bf16x8*)&smem[32768 + (c)*16384 + (kh)*8192 + rbBase + (nh)*1024 + jj*512]; } while (0)

#define MFMA_Q(nh) do {                                                       \
    __builtin_amdgcn_s_setprio(1);                                            \
    _Pragma("unroll")                                                         \
    for (int i = 0; i < 8; ++i)                                               \
        _Pragma("unroll")                                                     \
        for (int jj = 0; jj < 2; ++jj)                                        \
            acc[i][(nh)*2 + jj] = __builtin_amdgcn_mfma_f32_16x16x32_bf16(    \
                a[i], b[jj], acc[i][(nh)*2 + jj], 0, 0, 0);                   \
    __builtin_amdgcn_s_setprio(0); } while (0)

    f32x4 acc[8][4];
    #pragma unroll
    for (int i = 0; i < 8; ++i)
        #pragma unroll
        for (int j = 0; j < 4; ++j)
            #pragma unroll
            for (int r = 0; r < 4; ++r) acc[i][j][r] = 0.0f;

    // prologue: stage K-tile 0 (h0=A-k0, h1=B-k0, h2=A-k1, h3=B-k1)
    STAGE_A(0, 0, 0); STAGE_B(0, 0, 0); STAGE_A(0, 1, 0); STAGE_B(0, 1, 0);
    WVM4();           // h0,h1 landed (h2,h3 still in flight)
    BAR();

    #pragma unroll 1
    for (int kt = 0; kt < NT; ++kt) {
        const int cur = kt & 1, nxt = cur ^ 1;
        const long kN = (long)(kt + 1) * 64;
        const bool st = (kt + 1 < NT);
        bf16x8 a[8], b[2];

        // phase 0: (kh0, nh0)
        LOAD_A(cur, 0); LOAD_B(cur, 0, 0);
        if (st) STAGE_A(nxt, 0, kN);
        BAR(); WLGKM0(); __builtin_amdgcn_sched_barrier(0);
        MFMA_Q(0);
        BAR();
        // phase 1: (kh0, nh1)
        LOAD_B(cur, 0, 1);
        if (st) STAGE_B(nxt, 0, kN);
        BAR(); WLGKM0(); __builtin_amdgcn_sched_barrier(0);
        MFMA_Q(1);
        if (st) { WVM4(); } else { WVM0(); }   // h2,h3 of current tile landed
        BAR();
        // phase 2: (kh1, nh1)
        LOAD_A(cur, 1); LOAD_B(cur, 1, 1);
        if (st) STAGE_A(nxt, 1, kN);
        BAR(); WLGKM0(); __builtin_amdgcn_sched_barrier(0);
        MFMA_Q(1);
        BAR();
        // phase 3: (kh1, nh0)
        LOAD_B(cur, 1, 0);
        if (st) STAGE_B(nxt, 1, kN);
        BAR(); WLGKM0(); __builtin_amdgcn_sched_barrier(0);
        MFMA_Q(0);
        if (st) { WVM4(); } else { WVM0(); }   // next tile h0,h1 landed
        BAR();
    }

    // epilogue
    const long crow0 = m0 + wm * 128;
    const long ccol0 = n0 + wn * 64;
    #pragma unroll
    for (int i = 0; i < 8; ++i) {
        #pragma unroll
        for (int j = 0; j < 4; ++j) {
            const long col = ccol0 + j * 16 + lr;
            float bv_ = 0.0f;
            if (HAS_BIAS) bv_ = bias[col];
            if (OUT_MODE == 2) {
                const long row0 = crow0 + i * 16 + lk * 4;
                u16x4 pk;
                #pragma unroll
                for (int r = 0; r < 4; ++r) {
                    float v = acc[i][j][r] + bv_;
                    v *= scale;
                    pk[r] = f2b(v);
                }
                const long b_ = row0 >> 12, s_ = row0 & 4095;
                *(u16x4*)((u16*)Cout + (b_ << 22) + (col << 12) + s_) = pk;
            } else {
                #pragma unroll
                for (int r = 0; r < 4; ++r) {
                    const long row = crow0 + i * 16 + lk * 4 + r;
                    float v = acc[i][j][r];
                    if (HAS_BIAS) v += bv_;
                    v *= scale;
                    if (RELU) v = fmaxf(v, 0.0f);
                    if (HAS_RES) v += res[row * (long)N + col];
                    if (OUT_MODE == 1) Cf[row * (long)N + col] = v;
                    else               Cb[row * (long)N + col] = f2b(v);
                }
            }
        }
    }
#undef STAGE_A
#undef STAGE_B
#undef LOAD_A
#undef LOAD_B
#undef MFMA_Q
}

// ---------------------------------------------------------------------------
__global__ __launch_bounds__(256) void cvt_f32_bf16(
    const float* __restrict__ in, u16* __restrict__ out, long n)
{
    long i = ((long)blockIdx.x * 256 + threadIdx.x) * 4;
    if (i >= n) return;
    float4 f = *(const float4*)(in + i);
    u16x4 o;
    o[0] = f2b(f.x); o[1] = f2b(f.y); o[2] = f2b(f.z); o[3] = f2b(f.w);
    *(u16x4*)(out + i) = o;
}

__global__ __launch_bounds__(256) void transpose_to_bf16(
    const float* __restrict__ in, u16* __restrict__ out, int R, int C)
{
    __shared__ float tile[32][33];
    const int bx = blockIdx.x * 32;
    const int by = blockIdx.y * 32;
    const int tx = threadIdx.x, ty = threadIdx.y;
    #pragma unroll
    for (int i = 0; i < 32; i += 8)
        tile[ty + i][tx] = in[(long)(by + ty + i) * C + bx + tx];
    __syncthreads();
    #pragma unroll
    for (int i = 0; i < 32; i += 8)
        out[(long)(bx + ty + i) * R + by + tx] = f2b(tile[tx][ty + i]);
}

// in-place row softmax over n=4096 bf16 elements; one block per row.
__global__ __launch_bounds__(256) void softmax_rows(u16* __restrict__ P, int n)
{
    const int t = threadIdx.x;
    const int lane = t & 63, w = t >> 6;
    u16* row = P + (long)blockIdx.x * n;
    u16x8 a = *(const u16x8*)(row + t * 16);
    u16x8 b = *(const u16x8*)(row + t * 16 + 8);
    float v[16];
    #pragma unroll
    for (int i = 0; i < 8; ++i) { v[i] = b2f(a[i]); v[8 + i] = b2f(b[i]); }

    float mx = v[0];
    #pragma unroll
    for (int i = 1; i < 16; ++i) mx = fmaxf(mx, v[i]);
    #pragma unroll
    for (int o = 32; o > 0; o >>= 1) mx = fmaxf(mx, __shfl_xor(mx, o));
    __shared__ float red[8];
    if (lane == 0) red[w] = mx;
    __syncthreads();
    mx = fmaxf(fmaxf(red[0], red[1]), fmaxf(red[2], red[3]));

    float s = 0.0f;
    #pragma unroll
    for (int i = 0; i < 16; ++i) { v[i] = __expf(v[i] - mx); s += v[i]; }
    #pragma unroll
    for (int o = 32; o > 0; o >>= 1) s += __shfl_xor(s, o);
    if (lane == 0) red[4 + w] = s;
    __syncthreads();
    s = red[4] + red[5] + red[6] + red[7];
    const float inv = 1.0f / s;

    #pragma unroll
    for (int i = 0; i < 8; ++i) { a[i] = f2b(v[i] * inv); b[i] = f2b(v[8 + i] * inv); }
    *(u16x8*)(row + t * 16)     = a;
    *(u16x8*)(row + t * 16 + 8) = b;
}

// ---------------------------------------------------------------------------
extern "C" void kernel_launch(void* const* d_in, const int* in_sizes, int n_in,
                              void* d_out, int out_size, void* d_ws, size_t ws_size,
                              hipStream_t stream)
{
    (void)in_sizes; (void)n_in; (void)out_size;
    const float* x  = (const float*)d_in[0];
    const float* Wq = (const float*)d_in[1];
    const float* bq = (const float*)d_in[2];
    const float* Wk = (const float*)d_in[3];
    const float* bk = (const float*)d_in[4];
    const float* Wv = (const float*)d_in[5];
    const float* bv = (const float*)d_in[6];
    const float* W1 = (const float*)d_in[7];
    const float* b1 = (const float*)d_in[8];
    const float* W2 = (const float*)d_in[9];
    const float* b2 = (const float*)d_in[10];
    float* out = (float*)d_out;

    const int  B = 4, S = 4096, D = 1024;
    const long SD  = (long)S * D;           // 4 Mi
    const long BSD = (long)B * SD;          // 16 Mi
    const long SS  = (long)S * S;           // 16 Mi

    // workspace (u16 elements)
    u16* xb = (u16*)d_ws;        // [B*S, D]
    u16* Wt = xb + BSD;          // 5 x [D, D]
    u16* Qb = Wt + 5L * D * D;   // [B*S, D]   (later: h)
    u16* Kb = Qb + BSD;          // [B*S, D]   (later: x_res)
    u16* Vt = Kb + BSD;          // B x [D, S]
    u16* Pb = Vt + BSD;          // scores: B x [S,S] (big) or [S,S] (small)

    const size_t need_big = (size_t)(Pb - xb + (long)B * SS) * 2;
    const bool bigP = ws_size >= need_big;

    cvt_f32_bf16<<<dim3((unsigned)(BSD / 4 / 256)), 256, 0, stream>>>(x, xb, BSD);

    dim3 tb(32, 8);
    transpose_to_bf16<<<dim3(D / 32, D / 32), tb, 0, stream>>>(Wq, Wt + 0L * D * D, D, D);
    transpose_to_bf16<<<dim3(D / 32, D / 32), tb, 0, stream>>>(Wk, Wt + 1L * D * D, D, D);
    transpose_to_bf16<<<dim3(D / 32, D / 32), tb, 0, stream>>>(Wv, Wt + 2L * D * D, D, D);
    transpose_to_bf16<<<dim3(D / 32, D / 32), tb, 0, stream>>>(W1, Wt + 3L * D * D, D, D);
    transpose_to_bf16<<<dim3(D / 32, D / 32), tb, 0, stream>>>(W2, Wt + 4L * D * D, D, D);

    const dim3 gproj(D / 256, (B * S) / 256);    // (4, 64) = 256 blocks
    // Q, K projections (bf16 out); V projection written directly as V^T
    gemm256<1,0,0,0><<<gproj, 512, 0, stream>>>(xb, Wt + 0L*D*D, bq, nullptr, Qb,
        B*S, D, D, 0, 0, 0, 0, 1.0f);
    gemm256<1,0,0,0><<<gproj, 512, 0, stream>>>(xb, Wt + 1L*D*D, bk, nullptr, Kb,
        B*S, D, D, 0, 0, 0, 0, 1.0f);
    gemm256<1,0,0,2><<<gproj, 512, 0, stream>>>(xb, Wt + 2L*D*D, bv, nullptr, Vt,
        B*S, D, D, 0, 0, 0, 0, 1.0f);

    if (bigP) {
        // scores = Q K^T / 32, all batches at once
        gemm256<0,0,0,0><<<dim3(S/256, S/256, B), 512, 0, stream>>>(
            Qb, Kb, nullptr, nullptr, Pb, S, S, D, SD, SD, SS, 0, 0.03125f);
        softmax_rows<<<B * S, 256, 0, stream>>>(Pb, S);
        // x_res = x + P @ V  -> Kb
        gemm256<0,0,1,0><<<dim3(D/256, S/256, B), 512, 0, stream>>>(
            Pb, Vt, nullptr, x, Kb, S, D, S, SS, SD, SD, SD, 1.0f);
    } else {
        for (int b = 0; b < B; ++b) {
            gemm256<0,0,0,0><<<dim3(S/256, S/256), 512, 0, stream>>>(
                Qb + b*SD, Kb + b*SD, nullptr, nullptr, Pb, S, S, D, 0, 0, 0, 0, 0.03125f);
            softmax_rows<<<S, 256, 0, stream>>>(Pb, S);
            gemm256<0,0,1,0><<<dim3(D/256, S/256), 512, 0, stream>>>(
                Pb, Vt + b*SD, nullptr, x + b*SD, Kb + b*SD, S, D, S, 0, 0, 0, 0, 1.0f);
        }
    }

    // FFN: h = relu(x_res @ W1 + b1) -> Qb;  out = 2*(h @ W2 + b2) fp32
    gemm256<1,1,0,0><<<gproj, 512, 0, stream>>>(Kb, Wt + 3L*D*D, b1, nullptr, Qb,
        B*S, D, D, 0, 0, 0, 0, 1.0f);
    gemm256<1,0,0,1><<<gproj, 512, 0, stream>>>(Qb, Wt + 4L*D*D, b2, nullptr, out,
        B*S, D, D, 0, 0, 0, 0, 2.0f);
}

// Round 3
// 899.909 us; speedup vs baseline: 1.0666x; 1.0666x over previous
//
#include <hip/hip_runtime.h>
#include <stdint.h>

typedef unsigned short u16;
typedef __bf16 bf16x8 __attribute__((ext_vector_type(8)));
typedef float f32x4 __attribute__((ext_vector_type(4)));
typedef unsigned short u16x8 __attribute__((ext_vector_type(8)));
typedef unsigned short u16x4 __attribute__((ext_vector_type(4)));

__device__ __forceinline__ float b2f(u16 b) {
    return __uint_as_float(((unsigned)b) << 16);
}
__device__ __forceinline__ u16 f2b(float f) {
    unsigned u = __float_as_uint(f);
    unsigned r = (u + 0x7fffu + ((u >> 16) & 1u)) >> 16;  // RNE
    return (u16)r;
}

#define GLDS16(g, l) __builtin_amdgcn_global_load_lds(                        \
    (const __attribute__((address_space(1))) void*)(g),                       \
    (__attribute__((address_space(3))) void*)(l), 16, 0, 0)

// ---------------------------------------------------------------------------
// 128x128-tile GEMM body (m97 structure, round-1 proven) + chunked XCD
// swizzle: consecutive logical blocks (which share an A-row-panel) map to the
// SAME XCD so the panel is read once into that XCD's L2.
// C = epilogue(A @ Bt^T); A[M,K], Bt[N,K] bf16 row-major.
// OUT_MODE: 0 = bf16 [.,N], 1 = f32 [.,N], 2 = bf16 V^T scatter
//           (b = row>>12, Vt[b][col][row&4095], batch stride 1<<22).
// ---------------------------------------------------------------------------
template<int HAS_BIAS, int RELU, int HAS_RES, int OUT_MODE>
__device__ __forceinline__ void gemm_body(
    const u16* __restrict__ A, const u16* __restrict__ Bt,
    const float* __restrict__ bias, const float* __restrict__ res,
    void* __restrict__ Cout, int N, int K,
    long sA, long sB, long sC, long sR, float scale)
{
    __shared__ u16 sAt[128 * 64];
    __shared__ u16 sBt[128 * 64];

    // chunked XCD swizzle (bijective; all grids here have nwg % 8 == 0)
    const long nwg = (long)gridDim.x * gridDim.y * gridDim.z;
    long gid = ((long)blockIdx.z * gridDim.y + blockIdx.y) * gridDim.x + blockIdx.x;
    long logical = (nwg % 8 == 0) ? (gid & 7) * (nwg >> 3) + (gid >> 3) : gid;
    const int bx = (int)(logical % gridDim.x);
    long tmp = logical / gridDim.x;
    const int by = (int)(tmp % gridDim.y);
    const int bz = (int)(tmp / gridDim.y);

    A  += (long)bz * sA;
    Bt += (long)bz * sB;

    const int t    = threadIdx.x;
    const int lane = t & 63;
    const int wid  = t >> 6;
    const int wm   = wid >> 1, wn = wid & 1;
    const int lr   = lane & 15, lk = lane >> 4;
    const long m0  = (long)by * 128;
    const long n0  = (long)bx * 128;

    f32x4 acc[4][4];
    #pragma unroll
    for (int i = 0; i < 4; ++i)
        #pragma unroll
        for (int j = 0; j < 4; ++j)
            #pragma unroll
            for (int r = 0; r < 4; ++r) acc[i][j][r] = 0.0f;

    const u16* gA = A  + (m0 + (t >> 3)) * (long)K + (t & 7) * 8;
    const u16* gB = Bt + (n0 + (t >> 3)) * (long)K + (t & 7) * 8;
    u16* lA = sAt + (t & ~63) * 8;   // wave-uniform base; HW adds lane*16B
    u16* lB = sBt + (t & ~63) * 8;

    for (int k0 = 0; k0 < K; k0 += 64) {
        #pragma unroll
        for (int it = 0; it < 4; ++it) {
            GLDS16(gA + (long)it * 32 * K + k0, lA + it * 2048);
            GLDS16(gB + (long)it * 32 * K + k0, lB + it * 2048);
        }
        __syncthreads();
        #pragma unroll
        for (int ks = 0; ks < 2; ++ks) {
            bf16x8 af[4], bfr[4];
            #pragma unroll
            for (int i = 0; i < 4; ++i) {
                af[i]  = *(const bf16x8*)(sAt + (wm * 64 + i * 16 + lr) * 64 + ks * 32 + lk * 8);
                bfr[i] = *(const bf16x8*)(sBt + (wn * 64 + i * 16 + lr) * 64 + ks * 32 + lk * 8);
            }
            #pragma unroll
            for (int i = 0; i < 4; ++i)
                #pragma unroll
                for (int j = 0; j < 4; ++j)
                    acc[i][j] = __builtin_amdgcn_mfma_f32_16x16x32_bf16(
                        af[i], bfr[j], acc[i][j], 0, 0, 0);
        }
        __syncthreads();
    }

    // epilogue: C/D layout col = lane&15, row = (lane>>4)*4 + reg  [m89]
    const long crow0 = m0 + wm * 64;
    const long ccol0 = n0 + wn * 64;
    u16*   Cb = (u16*)Cout   + (long)bz * sC;
    float* Cf = (float*)Cout + (long)bz * sC;
    const float* resz = res + (long)bz * sR;
    #pragma unroll
    for (int i = 0; i < 4; ++i) {
        #pragma unroll
        for (int j = 0; j < 4; ++j) {
            const long col = ccol0 + j * 16 + lr;
            float bv_ = 0.0f;
            if (HAS_BIAS) bv_ = bias[col];
            if (OUT_MODE == 2) {
                const long row0 = crow0 + i * 16 + lk * 4;
                u16x4 pk;
                #pragma unroll
                for (int r = 0; r < 4; ++r) {
                    float v = acc[i][j][r] + bv_;
                    v *= scale;
                    pk[r] = f2b(v);
                }
                const long b_ = row0 >> 12, s_ = row0 & 4095;
                *(u16x4*)((u16*)Cout + (b_ << 22) + (col << 12) + s_) = pk;
            } else {
                #pragma unroll
                for (int r = 0; r < 4; ++r) {
                    const long row = crow0 + i * 16 + lk * 4 + r;
                    float v = acc[i][j][r];
                    if (HAS_BIAS) v += bv_;
                    v *= scale;
                    if (RELU) v = fmaxf(v, 0.0f);
                    if (HAS_RES) v += resz[row * (long)N + col];
                    if (OUT_MODE == 1) Cf[row * (long)N + col] = v;
                    else               Cb[row * (long)N + col] = f2b(v);
                }
            }
        }
    }
}

// distinct names per role for rocprof attribution ----------------------------
__global__ __launch_bounds__(256) void g_proj(
    const u16* A, const u16* Bt, const float* bias, u16* C, int N, int K)
{ gemm_body<1,0,0,0>(A, Bt, bias, nullptr, C, N, K, 0,0,0,0, 1.0f); }

__global__ __launch_bounds__(256) void g_vproj(
    const u16* A, const u16* Bt, const float* bias, u16* C, int N, int K)
{ gemm_body<1,0,0,2>(A, Bt, bias, nullptr, C, N, K, 0,0,0,0, 1.0f); }

__global__ __launch_bounds__(256) void g_qkt(
    const u16* A, const u16* Bt, u16* C, int N, int K,
    long sA, long sB, long sC, float scale)
{ gemm_body<0,0,0,0>(A, Bt, nullptr, nullptr, C, N, K, sA, sB, sC, 0, scale); }

__global__ __launch_bounds__(256) void g_pv(
    const u16* A, const u16* Bt, const float* res, u16* C, int N, int K,
    long sA, long sB, long sC, long sR)
{ gemm_body<0,0,1,0>(A, Bt, nullptr, res, C, N, K, sA, sB, sC, sR, 1.0f); }

__global__ __launch_bounds__(256) void g_ffn1(
    const u16* A, const u16* Bt, const float* bias, u16* C, int N, int K)
{ gemm_body<1,1,0,0>(A, Bt, bias, nullptr, C, N, K, 0,0,0,0, 1.0f); }

__global__ __launch_bounds__(256) void g_ffn2(
    const u16* A, const u16* Bt, const float* bias, float* C, int N, int K, float scale)
{ gemm_body<1,0,0,1>(A, Bt, bias, nullptr, C, N, K, 0,0,0,0, scale); }

// ---------------------------------------------------------------------------
__global__ __launch_bounds__(256) void cvt_f32_bf16(
    const float* __restrict__ in, u16* __restrict__ out, long n)
{
    long i = ((long)blockIdx.x * 256 + threadIdx.x) * 4;
    if (i >= n) return;
    float4 f = *(const float4*)(in + i);
    u16x4 o;
    o[0] = f2b(f.x); o[1] = f2b(f.y); o[2] = f2b(f.z); o[3] = f2b(f.w);
    *(u16x4*)(out + i) = o;
}

__global__ __launch_bounds__(256) void transpose_to_bf16(
    const float* __restrict__ in, u16* __restrict__ out, int R, int C)
{
    __shared__ float tile[32][33];
    const int bx = blockIdx.x * 32;
    const int by = blockIdx.y * 32;
    const int tx = threadIdx.x, ty = threadIdx.y;
    #pragma unroll
    for (int i = 0; i < 32; i += 8)
        tile[ty + i][tx] = in[(long)(by + ty + i) * C + bx + tx];
    __syncthreads();
    #pragma unroll
    for (int i = 0; i < 32; i += 8)
        out[(long)(bx + ty + i) * R + by + tx] = f2b(tile[tx][ty + i]);
}

// in-place row softmax over n=4096 bf16 elements; one block per row.
__global__ __launch_bounds__(256) void softmax_rows(u16* __restrict__ P, int n)
{
    const int t = threadIdx.x;
    const int lane = t & 63, w = t >> 6;
    u16* row = P + (long)blockIdx.x * n;
    u16x8 a = *(const u16x8*)(row + t * 16);
    u16x8 b = *(const u16x8*)(row + t * 16 + 8);
    float v[16];
    #pragma unroll
    for (int i = 0; i < 8; ++i) { v[i] = b2f(a[i]); v[8 + i] = b2f(b[i]); }

    float mx = v[0];
    #pragma unroll
    for (int i = 1; i < 16; ++i) mx = fmaxf(mx, v[i]);
    #pragma unroll
    for (int o = 32; o > 0; o >>= 1) mx = fmaxf(mx, __shfl_xor(mx, o));
    __shared__ float red[8];
    if (lane == 0) red[w] = mx;
    __syncthreads();
    mx = fmaxf(fmaxf(red[0], red[1]), fmaxf(red[2], red[3]));

    float s = 0.0f;
    #pragma unroll
    for (int i = 0; i < 16; ++i) { v[i] = __expf(v[i] - mx); s += v[i]; }
    #pragma unroll
    for (int o = 32; o > 0; o >>= 1) s += __shfl_xor(s, o);
    if (lane == 0) red[4 + w] = s;
    __syncthreads();
    s = red[4] + red[5] + red[6] + red[7];
    const float inv = 1.0f / s;

    #pragma unroll
    for (int i = 0; i < 8; ++i) { a[i] = f2b(v[i] * inv); b[i] = f2b(v[8 + i] * inv); }
    *(u16x8*)(row + t * 16)     = a;
    *(u16x8*)(row + t * 16 + 8) = b;
}

// ---------------------------------------------------------------------------
extern "C" void kernel_launch(void* const* d_in, const int* in_sizes, int n_in,
                              void* d_out, int out_size, void* d_ws, size_t ws_size,
                              hipStream_t stream)
{
    (void)in_sizes; (void)n_in; (void)out_size;
    const float* x  = (const float*)d_in[0];
    const float* Wq = (const float*)d_in[1];
    const float* bq = (const float*)d_in[2];
    const float* Wk = (const float*)d_in[3];
    const float* bk = (const float*)d_in[4];
    const float* Wv = (const float*)d_in[5];
    const float* bv = (const float*)d_in[6];
    const float* W1 = (const float*)d_in[7];
    const float* b1 = (const float*)d_in[8];
    const float* W2 = (const float*)d_in[9];
    const float* b2 = (const float*)d_in[10];
    float* out = (float*)d_out;

    const int  B = 4, S = 4096, D = 1024;
    const long SD  = (long)S * D;           // 4 Mi
    const long BSD = (long)B * SD;          // 16 Mi
    const long SS  = (long)S * S;           // 16 Mi

    // workspace (u16 elements)
    u16* xb = (u16*)d_ws;        // [B*S, D]
    u16* Wt = xb + BSD;          // 5 x [D, D]
    u16* Qb = Wt + 5L * D * D;   // [B*S, D]   (later: h)
    u16* Kb = Qb + BSD;          // [B*S, D]   (later: x_res)
    u16* Vt = Kb + BSD;          // B x [D, S]
    u16* Pb = Vt + BSD;          // scores: B x [S,S] (big) or [S,S] (small)

    const size_t need_big = (size_t)(Pb - xb + (long)B * SS) * 2;
    const bool bigP = ws_size >= need_big;

    cvt_f32_bf16<<<dim3((unsigned)(BSD / 4 / 256)), 256, 0, stream>>>(x, xb, BSD);

    dim3 tb(32, 8);
    transpose_to_bf16<<<dim3(D / 32, D / 32), tb, 0, stream>>>(Wq, Wt + 0L * D * D, D, D);
    transpose_to_bf16<<<dim3(D / 32, D / 32), tb, 0, stream>>>(Wk, Wt + 1L * D * D, D, D);
    transpose_to_bf16<<<dim3(D / 32, D / 32), tb, 0, stream>>>(Wv, Wt + 2L * D * D, D, D);
    transpose_to_bf16<<<dim3(D / 32, D / 32), tb, 0, stream>>>(W1, Wt + 3L * D * D, D, D);
    transpose_to_bf16<<<dim3(D / 32, D / 32), tb, 0, stream>>>(W2, Wt + 4L * D * D, D, D);

    const dim3 gproj(D / 128, (B * S) / 128);    // (8, 128) = 1024 blocks
    g_proj <<<gproj, 256, 0, stream>>>(xb, Wt + 0L*D*D, bq, Qb, D, D);
    g_proj <<<gproj, 256, 0, stream>>>(xb, Wt + 1L*D*D, bk, Kb, D, D);
    g_vproj<<<gproj, 256, 0, stream>>>(xb, Wt + 2L*D*D, bv, Vt, D, D);

    if (bigP) {
        g_qkt<<<dim3(S/128, S/128, B), 256, 0, stream>>>(
            Qb, Kb, Pb, S, D, SD, SD, SS, 0.03125f);
        softmax_rows<<<B * S, 256, 0, stream>>>(Pb, S);
        g_pv<<<dim3(D/128, S/128, B), 256, 0, stream>>>(
            Pb, Vt, x, Kb, D, S, SS, SD, SD, SD);
    } else {
        for (int b = 0; b < B; ++b) {
            g_qkt<<<dim3(S/128, S/128), 256, 0, stream>>>(
                Qb + b*SD, Kb + b*SD, Pb, S, D, 0, 0, 0, 0.03125f);
            softmax_rows<<<S, 256, 0, stream>>>(Pb, S);
            g_pv<<<dim3(D/128, S/128), 256, 0, stream>>>(
                Pb, Vt + b*SD, x + b*SD, Kb + b*SD, D, S, 0, 0, 0, 0);
        }
    }

    // FFN: h = relu(x_res @ W1 + b1) -> Qb;  out = 2*(h @ W2 + b2) fp32
    g_ffn1<<<gproj, 256, 0, stream>>>(Kb, Wt + 3L*D*D, b1, Qb, D, D);
    g_ffn2<<<gproj, 256, 0, stream>>>(Qb, Wt + 4L*D*D, b2, out, D, D, 2.0f);
}

// Round 4
// 735.624 us; speedup vs baseline: 1.3048x; 1.2233x over previous
//
#include <hip/hip_runtime.h>
#include <stdint.h>

typedef unsigned short u16;
typedef __bf16 bf16x8 __attribute__((ext_vector_type(8)));
typedef float f32x4 __attribute__((ext_vector_type(4)));
typedef unsigned short u16x8 __attribute__((ext_vector_type(8)));
typedef unsigned short u16x4 __attribute__((ext_vector_type(4)));

__device__ __forceinline__ float b2f(u16 b) {
    return __uint_as_float(((unsigned)b) << 16);
}
__device__ __forceinline__ u16 f2b(float f) {
    unsigned u = __float_as_uint(f);
    unsigned r = (u + 0x7fffu + ((u >> 16) & 1u)) >> 16;  // RNE
    return (u16)r;
}

#define GLDS16(g, l) __builtin_amdgcn_global_load_lds(                        \
    (const __attribute__((address_space(1))) void*)(g),                       \
    (__attribute__((address_space(3))) void*)(l), 16, 0, 0)

// ---------------------------------------------------------------------------
// 128x128-tile GEMM body (m97 structure) + chunked XCD swizzle.
// C = epilogue(A @ Bt^T); A[M,K], Bt[N,K] bf16 row-major.
// OUT_MODE: 0 = bf16 [.,N], 1 = f32 [.,N], 2 = bf16 V^T scatter
//           (b = row>>12, Vt[b][col][row&4095], batch stride 1<<22).
// ---------------------------------------------------------------------------
template<int HAS_BIAS, int RELU, int HAS_RES, int OUT_MODE>
__device__ __forceinline__ void gemm_body(
    const u16* __restrict__ A, const u16* __restrict__ Bt,
    const float* __restrict__ bias, const float* __restrict__ res,
    void* __restrict__ Cout, int N, int K,
    long sA, long sB, long sC, long sR, float scale)
{
    __shared__ u16 sAt[128 * 64];
    __shared__ u16 sBt[128 * 64];

    // chunked XCD swizzle (bijective; all grids here have nwg % 8 == 0)
    const long nwg = (long)gridDim.x * gridDim.y * gridDim.z;
    long gid = ((long)blockIdx.z * gridDim.y + blockIdx.y) * gridDim.x + blockIdx.x;
    long logical = (nwg % 8 == 0) ? (gid & 7) * (nwg >> 3) + (gid >> 3) : gid;
    const int bx = (int)(logical % gridDim.x);
    long tmp = logical / gridDim.x;
    const int by = (int)(tmp % gridDim.y);
    const int bz = (int)(tmp / gridDim.y);

    A  += (long)bz * sA;
    Bt += (long)bz * sB;

    const int t    = threadIdx.x;
    const int lane = t & 63;
    const int wid  = t >> 6;
    const int wm   = wid >> 1, wn = wid & 1;
    const int lr   = lane & 15, lk = lane >> 4;
    const long m0  = (long)by * 128;
    const long n0  = (long)bx * 128;

    f32x4 acc[4][4];
    #pragma unroll
    for (int i = 0; i < 4; ++i)
        #pragma unroll
        for (int j = 0; j < 4; ++j)
            #pragma unroll
            for (int r = 0; r < 4; ++r) acc[i][j][r] = 0.0f;

    const u16* gA = A  + (m0 + (t >> 3)) * (long)K + (t & 7) * 8;
    const u16* gB = Bt + (n0 + (t >> 3)) * (long)K + (t & 7) * 8;
    u16* lA = sAt + (t & ~63) * 8;   // wave-uniform base; HW adds lane*16B
    u16* lB = sBt + (t & ~63) * 8;

    for (int k0 = 0; k0 < K; k0 += 64) {
        #pragma unroll
        for (int it = 0; it < 4; ++it) {
            GLDS16(gA + (long)it * 32 * K + k0, lA + it * 2048);
            GLDS16(gB + (long)it * 32 * K + k0, lB + it * 2048);
        }
        __syncthreads();
        #pragma unroll
        for (int ks = 0; ks < 2; ++ks) {
            bf16x8 af[4], bfr[4];
            #pragma unroll
            for (int i = 0; i < 4; ++i) {
                af[i]  = *(const bf16x8*)(sAt + (wm * 64 + i * 16 + lr) * 64 + ks * 32 + lk * 8);
                bfr[i] = *(const bf16x8*)(sBt + (wn * 64 + i * 16 + lr) * 64 + ks * 32 + lk * 8);
            }
            #pragma unroll
            for (int i = 0; i < 4; ++i)
                #pragma unroll
                for (int j = 0; j < 4; ++j)
                    acc[i][j] = __builtin_amdgcn_mfma_f32_16x16x32_bf16(
                        af[i], bfr[j], acc[i][j], 0, 0, 0);
        }
        __syncthreads();
    }

    // epilogue: C/D layout col = lane&15, row = (lane>>4)*4 + reg  [m89]
    const long crow0 = m0 + wm * 64;
    const long ccol0 = n0 + wn * 64;
    u16*   Cb = (u16*)Cout   + (long)bz * sC;
    float* Cf = (float*)Cout + (long)bz * sC;
    const float* resz = res + (long)bz * sR;
    #pragma unroll
    for (int i = 0; i < 4; ++i) {
        #pragma unroll
        for (int j = 0; j < 4; ++j) {
            const long col = ccol0 + j * 16 + lr;
            float bv_ = 0.0f;
            if (HAS_BIAS) bv_ = bias[col];
            if (OUT_MODE == 2) {
                const long row0 = crow0 + i * 16 + lk * 4;
                u16x4 pk;
                #pragma unroll
                for (int r = 0; r < 4; ++r) {
                    float v = acc[i][j][r] + bv_;
                    v *= scale;
                    pk[r] = f2b(v);
                }
                const long b_ = row0 >> 12, s_ = row0 & 4095;
                *(u16x4*)((u16*)Cout + (b_ << 22) + (col << 12) + s_) = pk;
            } else {
                #pragma unroll
                for (int r = 0; r < 4; ++r) {
                    const long row = crow0 + i * 16 + lk * 4 + r;
                    float v = acc[i][j][r];
                    if (HAS_BIAS) v += bv_;
                    v *= scale;
                    if (RELU) v = fmaxf(v, 0.0f);
                    if (HAS_RES) v += resz[row * (long)N + col];
                    if (OUT_MODE == 1) Cf[row * (long)N + col] = v;
                    else               Cb[row * (long)N + col] = f2b(v);
                }
            }
        }
    }
}

// distinct names per role for rocprof attribution ----------------------------
__global__ __launch_bounds__(256) void g_proj(
    const u16* A, const u16* Bt, const float* bias, u16* C, int N, int K)
{ gemm_body<1,0,0,0>(A, Bt, bias, nullptr, C, N, K, 0,0,0,0, 1.0f); }

__global__ __launch_bounds__(256) void g_vproj(
    const u16* A, const u16* Bt, const float* bias, u16* C, int N, int K)
{ gemm_body<1,0,0,2>(A, Bt, bias, nullptr, C, N, K, 0,0,0,0, 1.0f); }

__global__ __launch_bounds__(256) void g_qkt(
    const u16* A, const u16* Bt, u16* C, int N, int K,
    long sA, long sB, long sC, float scale)
{ gemm_body<0,0,0,0>(A, Bt, nullptr, nullptr, C, N, K, sA, sB, sC, 0, scale); }

__global__ __launch_bounds__(256) void g_pv(
    const u16* A, const u16* Bt, const float* res, u16* C, int N, int K,
    long sA, long sB, long sC, long sR)
{ gemm_body<0,0,1,0>(A, Bt, nullptr, res, C, N, K, sA, sB, sC, sR, 1.0f); }

__global__ __launch_bounds__(256) void g_ffn1(
    const u16* A, const u16* Bt, const float* bias, u16* C, int N, int K)
{ gemm_body<1,1,0,0>(A, Bt, bias, nullptr, C, N, K, 0,0,0,0, 1.0f); }

__global__ __launch_bounds__(256) void g_ffn2(
    const u16* A, const u16* Bt, const float* bias, float* C, int N, int K, float scale)
{ gemm_body<1,0,0,1>(A, Bt, bias, nullptr, C, N, K, 0,0,0,0, scale); }

// ---------------------------------------------------------------------------
__global__ __launch_bounds__(256) void cvt_f32_bf16(
    const float* __restrict__ in, u16* __restrict__ out, long n)
{
    long i = ((long)blockIdx.x * 256 + threadIdx.x) * 4;
    if (i >= n) return;
    float4 f = *(const float4*)(in + i);
    u16x4 o;
    o[0] = f2b(f.x); o[1] = f2b(f.y); o[2] = f2b(f.z); o[3] = f2b(f.w);
    *(u16x4*)(out + i) = o;
}

__global__ __launch_bounds__(256) void transpose_to_bf16(
    const float* __restrict__ in, u16* __restrict__ out, int R, int C)
{
    __shared__ float tile[32][33];
    const int bx = blockIdx.x * 32;
    const int by = blockIdx.y * 32;
    const int tx = threadIdx.x, ty = threadIdx.y;
    #pragma unroll
    for (int i = 0; i < 32; i += 8)
        tile[ty + i][tx] = in[(long)(by + ty + i) * C + bx + tx];
    __syncthreads();
    #pragma unroll
    for (int i = 0; i < 32; i += 8)
        out[(long)(bx + ty + i) * R + by + tx] = f2b(tile[tx][ty + i]);
}

// in-place row softmax over n=4096 bf16 elements; one block per row.
__global__ __launch_bounds__(256) void softmax_rows(u16* __restrict__ P, int n)
{
    const int t = threadIdx.x;
    const int lane = t & 63, w = t >> 6;
    u16* row = P + (long)blockIdx.x * n;
    u16x8 a = *(const u16x8*)(row + t * 16);
    u16x8 b = *(const u16x8*)(row + t * 16 + 8);
    float v[16];
    #pragma unroll
    for (int i = 0; i < 8; ++i) { v[i] = b2f(a[i]); v[8 + i] = b2f(b[i]); }

    float mx = v[0];
    #pragma unroll
    for (int i = 1; i < 16; ++i) mx = fmaxf(mx, v[i]);
    #pragma unroll
    for (int o = 32; o > 0; o >>= 1) mx = fmaxf(mx, __shfl_xor(mx, o));
    __shared__ float red[8];
    if (lane == 0) red[w] = mx;
    __syncthreads();
    mx = fmaxf(fmaxf(red[0], red[1]), fmaxf(red[2], red[3]));

    float s = 0.0f;
    #pragma unroll
    for (int i = 0; i < 16; ++i) { v[i] = __expf(v[i] - mx); s += v[i]; }
    #pragma unroll
    for (int o = 32; o > 0; o >>= 1) s += __shfl_xor(s, o);
    if (lane == 0) red[4 + w] = s;
    __syncthreads();
    s = red[4] + red[5] + red[6] + red[7];
    const float inv = 1.0f / s;

    #pragma unroll
    for (int i = 0; i < 8; ++i) { a[i] = f2b(v[i] * inv); b[i] = f2b(v[8 + i] * inv); }
    *(u16x8*)(row + t * 16)     = a;
    *(u16x8*)(row + t * 16 + 8) = b;
}

// ---------------------------------------------------------------------------
extern "C" void kernel_launch(void* const* d_in, const int* in_sizes, int n_in,
                              void* d_out, int out_size, void* d_ws, size_t ws_size,
                              hipStream_t stream)
{
    (void)in_sizes; (void)n_in; (void)out_size;
    const float* x  = (const float*)d_in[0];
    const float* Wq = (const float*)d_in[1];
    const float* bq = (const float*)d_in[2];
    const float* Wk = (const float*)d_in[3];
    const float* bk = (const float*)d_in[4];
    const float* Wv = (const float*)d_in[5];
    const float* bv = (const float*)d_in[6];
    const float* W1 = (const float*)d_in[7];
    const float* b1 = (const float*)d_in[8];
    const float* W2 = (const float*)d_in[9];
    const float* b2 = (const float*)d_in[10];
    float* out = (float*)d_out;

    const int  B = 4, S = 4096, D = 1024;
    const long SD  = (long)S * D;           // 4 Mi
    const long BSD = (long)B * SD;          // 16 Mi
    const long SS  = (long)S * S;           // 16 Mi

    // pick score-chunk size BC (batches per attention chunk): P buffer holds
    // BC*SS elements and aliases xb (x_bf16 is dead after the projections).
    // bytes(BC) = (BC*SS + 5*D*D + 3*BSD) * 2
    int BC = 4;
    while (BC > 1 && (size_t)((long)BC * SS + 5L * D * D + 3L * BSD) * 2 > ws_size)
        BC >>= 1;

    // workspace layout (u16 elements)
    u16* Pb = (u16*)d_ws;            // [BC, S, S] scores; xb aliases Pb
    u16* xb = Pb;                    // [B*S, D] x bf16 (dead after proj)
    u16* Wt = Pb + (long)BC * SS;    // 5 x [D, D]
    u16* Qb = Wt + 5L * D * D;       // [B*S, D]   (later: h)
    u16* Kb = Qb + BSD;              // [B*S, D]   (later: x_res)
    u16* Vt = Kb + BSD;              // B x [D, S]

    cvt_f32_bf16<<<dim3((unsigned)(BSD / 4 / 256)), 256, 0, stream>>>(x, xb, BSD);

    dim3 tb(32, 8);
    transpose_to_bf16<<<dim3(D / 32, D / 32), tb, 0, stream>>>(Wq, Wt + 0L * D * D, D, D);
    transpose_to_bf16<<<dim3(D / 32, D / 32), tb, 0, stream>>>(Wk, Wt + 1L * D * D, D, D);
    transpose_to_bf16<<<dim3(D / 32, D / 32), tb, 0, stream>>>(Wv, Wt + 2L * D * D, D, D);
    transpose_to_bf16<<<dim3(D / 32, D / 32), tb, 0, stream>>>(W1, Wt + 3L * D * D, D, D);
    transpose_to_bf16<<<dim3(D / 32, D / 32), tb, 0, stream>>>(W2, Wt + 4L * D * D, D, D);

    const dim3 gproj(D / 128, (B * S) / 128);    // (8, 128) = 1024 blocks
    g_proj <<<gproj, 256, 0, stream>>>(xb, Wt + 0L*D*D, bq, Qb, D, D);
    g_proj <<<gproj, 256, 0, stream>>>(xb, Wt + 1L*D*D, bk, Kb, D, D);
    g_vproj<<<gproj, 256, 0, stream>>>(xb, Wt + 2L*D*D, bv, Vt, D, D);
    // xb is dead from here; Pb may overwrite it.

    for (int c = 0; c < B; c += BC) {
        g_qkt<<<dim3(S/128, S/128, BC), 256, 0, stream>>>(
            Qb + (long)c * SD, Kb + (long)c * SD, Pb, S, D, SD, SD, SS, 0.03125f);
        softmax_rows<<<BC * S, 256, 0, stream>>>(Pb, S);
        g_pv<<<dim3(D/128, S/128, BC), 256, 0, stream>>>(
            Pb, Vt + (long)c * SD, x + (long)c * SD, Kb + (long)c * SD,
            D, S, SS, SD, SD, SD);
    }

    // FFN: h = relu(x_res @ W1 + b1) -> Qb;  out = 2*(h @ W2 + b2) fp32
    g_ffn1<<<gproj, 256, 0, stream>>>(Kb, Wt + 3L*D*D, b1, Qb, D, D);
    g_ffn2<<<gproj, 256, 0, stream>>>(Qb, Wt + 4L*D*D, b2, out, D, D, 2.0f);
}

// Round 5
// 535.961 us; speedup vs baseline: 1.7909x; 1.3725x over previous
//
#include <hip/hip_runtime.h>
#include <stdint.h>

typedef unsigned short u16;
typedef __bf16 bf16x8 __attribute__((ext_vector_type(8)));
typedef float f32x4 __attribute__((ext_vector_type(4)));
typedef unsigned short u16x8 __attribute__((ext_vector_type(8)));
typedef unsigned short u16x4 __attribute__((ext_vector_type(4)));

__device__ __forceinline__ float b2f(u16 b) {
    return __uint_as_float(((unsigned)b) << 16);
}
__device__ __forceinline__ u16 f2b(float f) {
    unsigned u = __float_as_uint(f);
    unsigned r = (u + 0x7fffu + ((u >> 16) & 1u)) >> 16;  // RNE
    return (u16)r;
}

#define GLDS16(g, l) __builtin_amdgcn_global_load_lds(                        \
    (const __attribute__((address_space(1))) void*)(g),                       \
    (__attribute__((address_space(3))) void*)(l), 16, 0, 0)

#define BAR()  __builtin_amdgcn_s_barrier()
#define LG0()  do { asm volatile("s_waitcnt lgkmcnt(0)" ::: "memory");        \
                    __builtin_amdgcn_sched_barrier(0); } while (0)
#define VMC(n) asm volatile("s_waitcnt vmcnt(" #n ")" ::: "memory")

// ---------------------------------------------------------------------------
// 256x256-tile, 8-phase (per 2 K-tiles), counted-vmcnt GEMM.
// C = epilogue(A @ Bt^T); A[M,K], Bt[N,K] bf16 row-major.
// 512 thr = 8 waves (2M x 4N); per-wave C = 128x64; BK=64 split into 2
// K-halves stored [256][32] elem (64B rows -> conflict-free frag reads).
// Schedule per K-tile t (buffers cur/nxt alternate):
//   P1: ds a(kk0,i0-3)+b(kk0) [8] | stage(nxt,A-kk0) | BAR lgkm0 16xMFMA BAR
//   P2: ds a(kk0,i4-7)        [4] | stage(nxt,B-kk0) | BAR lgkm0 16xMFMA
//       vmcnt(4)  <- tile t's A/B-kk1 (staged t-1.P3/P4) landed        BAR
//   P3: ds a(kk1,i0-3)+b(kk1) [8] | stage(nxt,A-kk1) | BAR lgkm0 16xMFMA BAR
//   P4: ds a(kk1,i4-7)        [4] | stage(nxt,B-kk1) | BAR lgkm0 16xMFMA
//       vmcnt(4)  <- tile t+1's A/B-kk0 (staged t.P1/P2) landed        BAR
// Ledger: exactly 8 loads outstanding at each checkpoint; every half has a
// full-K-tile flight time; stage targets slots free >=1 barrier earlier.
// OUT_MODE: 0 = bf16 [.,N], 1 = f32 [.,N], 2 = bf16 V^T scatter
//           (b = row>>12, Vt[b][col][row&4095], batch stride 1<<22).
// ---------------------------------------------------------------------------
template<int HAS_BIAS, int RELU, int HAS_RES, int OUT_MODE>
__device__ __forceinline__ void gemm8_body(
    const u16* __restrict__ A, const u16* __restrict__ Bt,
    const float* __restrict__ bias, const float* __restrict__ res,
    void* __restrict__ Cout, int N, int K,
    long sA, long sB, long sC, long sR, float scale)
{
    __shared__ u16 smem[65536];   // 128 KiB: A [buf][kk] 16KB x4, then B x4

    // chunked XCD swizzle (bijective; all grids here have nwg % 8 == 0)
    const long nwg = (long)gridDim.x * gridDim.y * gridDim.z;
    long gid = ((long)blockIdx.z * gridDim.y + blockIdx.y) * gridDim.x + blockIdx.x;
    long logical = (nwg % 8 == 0) ? (gid & 7) * (nwg >> 3) + (gid >> 3) : gid;
    const int bx = (int)(logical % gridDim.x);
    long tmp = logical / gridDim.x;
    const int by = (int)(tmp % gridDim.y);
    const int bz = (int)(tmp / gridDim.y);

    A  += (long)bz * sA;
    Bt += (long)bz * sB;

    const int tid  = threadIdx.x;
    const int lane = tid & 63, wid = tid >> 6;
    const int wm   = wid >> 2, wn = wid & 3;
    const int lr   = lane & 15, lk = lane >> 4;
    const long m0  = (long)by * 256;
    const long n0  = (long)bx * 256;
    const int  NT  = K >> 6;

    // staging: thread tid covers row tid>>2 (+128 for 2nd load), k-chunk
    // (tid&3)*8 of a [256][32] half; LDS dest wave-uniform + lane*16B.
    const u16* gA0 = A  + (m0 + (tid >> 2)) * (long)K + (tid & 3) * 8;
    const u16* gB0 = Bt + (n0 + (tid >> 2)) * (long)K + (tid & 3) * 8;
    const u16* gA1 = gA0 + 128L * K;
    const u16* gB1 = gB0 + 128L * K;
    const int wdst = (tid & ~63) * 8;   // u16 elems

#define STA(bufn, kk, kof) do {                                               \
    GLDS16(gA0 + (kof) + (kk) * 32, &smem[(bufn)*16384 + (kk)*8192 + wdst]);  \
    GLDS16(gA1 + (kof) + (kk) * 32, &smem[(bufn)*16384 + (kk)*8192 + wdst + 4096]); } while (0)
#define STB(bufn, kk, kof) do {                                               \
    GLDS16(gB0 + (kof) + (kk) * 32, &smem[32768 + (bufn)*16384 + (kk)*8192 + wdst]); \
    GLDS16(gB1 + (kof) + (kk) * 32, &smem[32768 + (bufn)*16384 + (kk)*8192 + wdst + 4096]); } while (0)

    const int raOff = (wm * 128 + lr) * 32 + lk * 8;   // + i*512 per frag
    const int rbOff = (wn * 64  + lr) * 32 + lk * 8;   // + j*512 per frag

#define LDA(kk, ih) do { _Pragma("unroll")                                    \
    for (int i = 0; i < 4; ++i)                                               \
        a[i] = *(const bf16x8*)&smem[cur*16384 + (kk)*8192 + raOff + ((ih)*4 + i)*512]; } while (0)
#define LDB(kk) do { _Pragma("unroll")                                        \
    for (int j = 0; j < 4; ++j)                                               \
        b[j] = *(const bf16x8*)&smem[32768 + cur*16384 + (kk)*8192 + rbOff + j*512]; } while (0)
#define MF(ih) do { __builtin_amdgcn_s_setprio(1); _Pragma("unroll")          \
    for (int i = 0; i < 4; ++i) _Pragma("unroll")                             \
        for (int j = 0; j < 4; ++j)                                           \
            acc[(ih)*4 + i][j] = __builtin_amdgcn_mfma_f32_16x16x32_bf16(     \
                a[i], b[j], acc[(ih)*4 + i][j], 0, 0, 0);                     \
    __builtin_amdgcn_s_setprio(0); } while (0)

    f32x4 acc[8][4];
    #pragma unroll
    for (int i = 0; i < 8; ++i)
        #pragma unroll
        for (int j = 0; j < 4; ++j)
            #pragma unroll
            for (int r = 0; r < 4; ++r) acc[i][j][r] = 0.0f;

    bf16x8 a[4], b[4];

    // prologue: tile 0's four halves; wait A0,B0 (oldest 4 loads).
    STA(0, 0, 0); STB(0, 0, 0); STA(0, 1, 0); STB(0, 1, 0);
    VMC(4);
    BAR();

    int cur = 0;
    #pragma unroll 1
    for (int t = 0; t < NT - 1; ++t) {
        const long kof = (long)(t + 1) * 64;
        const int nxt = cur ^ 1;
        LDA(0, 0); LDB(0); STA(nxt, 0, kof);
        BAR(); LG0(); MF(0); BAR();
        LDA(0, 1);         STB(nxt, 0, kof);
        BAR(); LG0(); MF(1); VMC(4); BAR();
        LDA(1, 0); LDB(1); STA(nxt, 1, kof);
        BAR(); LG0(); MF(0); BAR();
        LDA(1, 1);         STB(nxt, 1, kof);
        BAR(); LG0(); MF(1); VMC(4); BAR();
        cur = nxt;
    }
    // tail tile (no staging)
    LDA(0, 0); LDB(0); BAR(); LG0(); MF(0); BAR();
    LDA(0, 1);         BAR(); LG0(); MF(1); VMC(0); BAR();
    LDA(1, 0); LDB(1); BAR(); LG0(); MF(0); BAR();
    LDA(1, 1);         BAR(); LG0(); MF(1);

    // epilogue: C/D layout col = lane&15, row = (lane>>4)*4 + reg  [m89]
    const long crow0 = m0 + wm * 128;
    const long ccol0 = n0 + wn * 64;
    u16*   Cb = (u16*)Cout   + (long)bz * sC;
    float* Cf = (float*)Cout + (long)bz * sC;
    const float* resz = res + (long)bz * sR;
    #pragma unroll
    for (int i = 0; i < 8; ++i) {
        #pragma unroll
        for (int j = 0; j < 4; ++j) {
            const long col = ccol0 + j * 16 + lr;
            float bv_ = 0.0f;
            if (HAS_BIAS) bv_ = bias[col];
            if (OUT_MODE == 2) {
                const long row0 = crow0 + i * 16 + lk * 4;
                u16x4 pk;
                #pragma unroll
                for (int r = 0; r < 4; ++r) {
                    float v = acc[i][j][r] + bv_;
                    v *= scale;
                    pk[r] = f2b(v);
                }
                const long b_ = row0 >> 12, s_ = row0 & 4095;
                *(u16x4*)((u16*)Cout + (b_ << 22) + (col << 12) + s_) = pk;
            } else {
                #pragma unroll
                for (int r = 0; r < 4; ++r) {
                    const long row = crow0 + i * 16 + lk * 4 + r;
                    float v = acc[i][j][r];
                    if (HAS_BIAS) v += bv_;
                    v *= scale;
                    if (RELU) v = fmaxf(v, 0.0f);
                    if (HAS_RES) v += resz[row * (long)N + col];
                    if (OUT_MODE == 1) Cf[row * (long)N + col] = v;
                    else               Cb[row * (long)N + col] = f2b(v);
                }
            }
        }
    }
#undef STA
#undef STB
#undef LDA
#undef LDB
#undef MF
}

// distinct names per role for rocprof attribution ----------------------------
__global__ __launch_bounds__(512, 2) void g8_proj(
    const u16* A, const u16* Bt, const float* bias, u16* C, int N, int K)
{ gemm8_body<1,0,0,0>(A, Bt, bias, nullptr, C, N, K, 0,0,0,0, 1.0f); }

__global__ __launch_bounds__(512, 2) void g8_vproj(
    const u16* A, const u16* Bt, const float* bias, u16* C, int N, int K)
{ gemm8_body<1,0,0,2>(A, Bt, bias, nullptr, C, N, K, 0,0,0,0, 1.0f); }

__global__ __launch_bounds__(512, 2) void g8_qkt(
    const u16* A, const u16* Bt, u16* C, int N, int K,
    long sA, long sB, long sC, float scale)
{ gemm8_body<0,0,0,0>(A, Bt, nullptr, nullptr, C, N, K, sA, sB, sC, 0, scale); }

__global__ __launch_bounds__(512, 2) void g8_pv(
    const u16* A, const u16* Bt, const float* res, u16* C, int N, int K,
    long sA, long sB, long sC, long sR)
{ gemm8_body<0,0,1,0>(A, Bt, nullptr, res, C, N, K, sA, sB, sC, sR, 1.0f); }

__global__ __launch_bounds__(512, 2) void g8_ffn1(
    const u16* A, const u16* Bt, const float* bias, u16* C, int N, int K)
{ gemm8_body<1,1,0,0>(A, Bt, bias, nullptr, C, N, K, 0,0,0,0, 1.0f); }

__global__ __launch_bounds__(512, 2) void g8_ffn2(
    const u16* A, const u16* Bt, const float* bias, float* C, int N, int K, float scale)
{ gemm8_body<1,0,0,1>(A, Bt, bias, nullptr, C, N, K, 0,0,0,0, scale); }

// ---------------------------------------------------------------------------
__global__ __launch_bounds__(256) void cvt_f32_bf16(
    const float* __restrict__ in, u16* __restrict__ out, long n)
{
    long i = ((long)blockIdx.x * 256 + threadIdx.x) * 4;
    if (i >= n) return;
    float4 f = *(const float4*)(in + i);
    u16x4 o;
    o[0] = f2b(f.x); o[1] = f2b(f.y); o[2] = f2b(f.z); o[3] = f2b(f.w);
    *(u16x4*)(out + i) = o;
}

__global__ __launch_bounds__(256) void transpose_to_bf16(
    const float* __restrict__ in, u16* __restrict__ out, int R, int C)
{
    __shared__ float tile[32][33];
    const int bx = blockIdx.x * 32;
    const int by = blockIdx.y * 32;
    const int tx = threadIdx.x, ty = threadIdx.y;
    #pragma unroll
    for (int i = 0; i < 32; i += 8)
        tile[ty + i][tx] = in[(long)(by + ty + i) * C + bx + tx];
    __syncthreads();
    #pragma unroll
    for (int i = 0; i < 32; i += 8)
        out[(long)(bx + ty + i) * R + by + tx] = f2b(tile[tx][ty + i]);
}

// in-place row softmax over n=4096 bf16 elements; one block per row.
__global__ __launch_bounds__(256) void softmax_rows(u16* __restrict__ P, int n)
{
    const int t = threadIdx.x;
    const int lane = t & 63, w = t >> 6;
    u16* row = P + (long)blockIdx.x * n;
    u16x8 a = *(const u16x8*)(row + t * 16);
    u16x8 b = *(const u16x8*)(row + t * 16 + 8);
    float v[16];
    #pragma unroll
    for (int i = 0; i < 8; ++i) { v[i] = b2f(a[i]); v[8 + i] = b2f(b[i]); }

    float mx = v[0];
    #pragma unroll
    for (int i = 1; i < 16; ++i) mx = fmaxf(mx, v[i]);
    #pragma unroll
    for (int o = 32; o > 0; o >>= 1) mx = fmaxf(mx, __shfl_xor(mx, o));
    __shared__ float red[8];
    if (lane == 0) red[w] = mx;
    __syncthreads();
    mx = fmaxf(fmaxf(red[0], red[1]), fmaxf(red[2], red[3]));

    float s = 0.0f;
    #pragma unroll
    for (int i = 0; i < 16; ++i) { v[i] = __expf(v[i] - mx); s += v[i]; }
    #pragma unroll
    for (int o = 32; o > 0; o >>= 1) s += __shfl_xor(s, o);
    if (lane == 0) red[4 + w] = s;
    __syncthreads();
    s = red[4] + red[5] + red[6] + red[7];
    const float inv = 1.0f / s;

    #pragma unroll
    for (int i = 0; i < 8; ++i) { a[i] = f2b(v[i] * inv); b[i] = f2b(v[8 + i] * inv); }
    *(u16x8*)(row + t * 16)     = a;
    *(u16x8*)(row + t * 16 + 8) = b;
}

// ---------------------------------------------------------------------------
extern "C" void kernel_launch(void* const* d_in, const int* in_sizes, int n_in,
                              void* d_out, int out_size, void* d_ws, size_t ws_size,
                              hipStream_t stream)
{
    (void)in_sizes; (void)n_in; (void)out_size;
    const float* x  = (const float*)d_in[0];
    const float* Wq = (const float*)d_in[1];
    const float* bq = (const float*)d_in[2];
    const float* Wk = (const float*)d_in[3];
    const float* bk = (const float*)d_in[4];
    const float* Wv = (const float*)d_in[5];
    const float* bv = (const float*)d_in[6];
    const float* W1 = (const float*)d_in[7];
    const float* b1 = (const float*)d_in[8];
    const float* W2 = (const float*)d_in[9];
    const float* b2 = (const float*)d_in[10];
    float* out = (float*)d_out;

    const int  B = 4, S = 4096, D = 1024;
    const long SD  = (long)S * D;           // 4 Mi
    const long BSD = (long)B * SD;          // 16 Mi
    const long SS  = (long)S * S;           // 16 Mi

    // score-chunk size BC: P holds BC*SS elems, aliasing xb (dead after proj)
    int BC = 4;
    while (BC > 1 && (size_t)((long)BC * SS + 5L * D * D + 3L * BSD) * 2 > ws_size)
        BC >>= 1;

    // workspace layout (u16 elements)
    u16* Pb = (u16*)d_ws;            // [BC, S, S] scores; xb aliases Pb
    u16* xb = Pb;                    // [B*S, D] x bf16 (dead after proj)
    u16* Wt = Pb + (long)BC * SS;    // 5 x [D, D]
    u16* Qb = Wt + 5L * D * D;       // [B*S, D]   (later: h)
    u16* Kb = Qb + BSD;              // [B*S, D]   (later: x_res)
    u16* Vt = Kb + BSD;              // B x [D, S]

    cvt_f32_bf16<<<dim3((unsigned)(BSD / 4 / 256)), 256, 0, stream>>>(x, xb, BSD);

    dim3 tb(32, 8);
    transpose_to_bf16<<<dim3(D / 32, D / 32), tb, 0, stream>>>(Wq, Wt + 0L * D * D, D, D);
    transpose_to_bf16<<<dim3(D / 32, D / 32), tb, 0, stream>>>(Wk, Wt + 1L * D * D, D, D);
    transpose_to_bf16<<<dim3(D / 32, D / 32), tb, 0, stream>>>(Wv, Wt + 2L * D * D, D, D);
    transpose_to_bf16<<<dim3(D / 32, D / 32), tb, 0, stream>>>(W1, Wt + 3L * D * D, D, D);
    transpose_to_bf16<<<dim3(D / 32, D / 32), tb, 0, stream>>>(W2, Wt + 4L * D * D, D, D);

    const dim3 gproj(D / 256, (B * S) / 256);    // (4, 64) = 256 blocks
    g8_proj <<<gproj, 512, 0, stream>>>(xb, Wt + 0L*D*D, bq, Qb, D, D);
    g8_proj <<<gproj, 512, 0, stream>>>(xb, Wt + 1L*D*D, bk, Kb, D, D);
    g8_vproj<<<gproj, 512, 0, stream>>>(xb, Wt + 2L*D*D, bv, Vt, D, D);
    // xb is dead from here; Pb may overwrite it.

    for (int c = 0; c < B; c += BC) {
        g8_qkt<<<dim3(S/256, S/256, BC), 512, 0, stream>>>(
            Qb + (long)c * SD, Kb + (long)c * SD, Pb, S, D, SD, SD, SS, 0.03125f);
        softmax_rows<<<BC * S, 256, 0, stream>>>(Pb, S);
        g8_pv<<<dim3(D/256, S/256, BC), 512, 0, stream>>>(
            Pb, Vt + (long)c * SD, x + (long)c * SD, Kb + (long)c * SD,
            D, S, SS, SD, SD, SD);
    }

    // FFN: h = relu(x_res @ W1 + b1) -> Qb;  out = 2*(h @ W2 + b2) fp32
    g8_ffn1<<<gproj, 512, 0, stream>>>(Kb, Wt + 3L*D*D, b1, Qb, D, D);
    g8_ffn2<<<gproj, 512, 0, stream>>>(Qb, Wt + 4L*D*D, b2, out, D, D, 2.0f);
}